// Round 7
// baseline (341.132 us; speedup 1.0000x reference)
//
#include <hip/hip_runtime.h>
#include <hip/hip_fp16.h>

#define NDIM 128     // OUT_DIM
#define KDIM 256     // IN_DIM
#define MT 5         // M-tiles (of 16 rows) per GEMM pipeline
#define AROW 264     // LDS A-row stride in halfs (16B-aligned, breaks pow2)
#define CHUNK 3200   // edges per phase1/phase3 block (500 blocks)
#define BSH 9        // bucket = 512 nodes
#define BMASK 511
#define MAXBUCK 256  // >= NBUCK = ceil(N/512) = 196
#define FTH 512      // fused kernel threads
#define ECAP 12032   // k_fine LDS staging capacity (48KB); mean run 8192, max ~8.8K
#define SFLAG 0x40000000
// LDS pool: fine needs (512+512+12032)*4 = 52224 B; gemm needs 2*2*16*AROW*2 = 33792 B
#define SMEM_BYTES 52224

typedef _Float16 half8 __attribute__((ext_vector_type(8)));
typedef _Float16 half4v __attribute__((ext_vector_type(4)));
typedef _Float16 half2v __attribute__((ext_vector_type(2)));
typedef float float4v __attribute__((ext_vector_type(4)));

#if __has_builtin(__builtin_amdgcn_fdot2)
#define HAS_FDOT2 1
#else
#define HAS_FDOT2 0
#endif

// ---------- K1: fused [phase1 histogram + global cnt | combine_w].
// blocks 0..NBLK-1: per-block coarse histogram (bucket = tgt>>9) + cnt atomics
// blocks NBLK..NBLK+127: Wc = Wg @ Wp in MFMA B-fragment layout
// block 0 additionally zeroes the scan-lookback flags (replay-safe).
__global__ __launch_bounds__(256) void k_prep(const float* __restrict__ Wp,
                                              const float* __restrict__ Wg,
                                              _Float16* __restrict__ Bfrag,
                                              const int* __restrict__ ei, int E,
                                              int* __restrict__ hist, int NBLK, int NBUCK,
                                              int* __restrict__ cnt,
                                              int* __restrict__ partials) {
    __shared__ int h[MAXBUCK];
    int tid = threadIdx.x;
    int blk = blockIdx.x;
    if (blk < NBLK) {
        // ---- phase1 (+ per-node degree via global atomics)
        if (blk == 0 && tid < 128) partials[tid] = 0;   // NSB <= 128
        const int* __restrict__ col = ei + E;
        h[tid] = 0;
        __syncthreads();
        int e0 = blk * CHUNK;
        int e1 = min(e0 + CHUNK, E);
        int lim = e1 - e0;
        int lim4 = lim >> 2;
        const int4* __restrict__ cv = (const int4*)(col + e0);
        for (int q = tid; q < lim4; q += 256) {
            int4 c = cv[q];
            atomicAdd(&h[c.x >> BSH], 1); atomicAdd(&cnt[c.x], 1);
            atomicAdd(&h[c.y >> BSH], 1); atomicAdd(&cnt[c.y], 1);
            atomicAdd(&h[c.z >> BSH], 1); atomicAdd(&cnt[c.z], 1);
            atomicAdd(&h[c.w >> BSH], 1); atomicAdd(&cnt[c.w], 1);
        }
        if (tid < (lim & 3)) {
            int c = col[e0 + lim4 * 4 + tid];
            atomicAdd(&h[c >> BSH], 1); atomicAdd(&cnt[c], 1);
        }
        __syncthreads();
        if (tid < NBUCK) hist[tid * NBLK + blk] = h[tid];
    } else {
        // ---- combine_w
        int o = blk - NBLK;      // n: 0..127
        int i = tid;             // k: 0..255
        float acc = 0.f;
#pragma unroll 4
        for (int k = 0; k < 128; ++k) acc = fmaf(Wg[o * 128 + k], Wp[k * 256 + i], acc);
        int kk = i >> 5, r = i & 31, quad = r >> 3, j = r & 7;
        int ntile = o >> 4, lanen = o & 15, lane = quad * 16 + lanen;
        Bfrag[(((ntile * 8 + kk) * 64) + lane) * 8 + j] = (_Float16)acc;
    }
}

// ---------- K2: single-kernel exclusive scan via aggregate lookback.
// 96 blocks x 1024 threads, all co-resident (96 << 256 CUs) -> spin is safe.
__global__ __launch_bounds__(1024) void k_scan_lb(int* __restrict__ a, int n,
                                                  int* __restrict__ partials) {
    __shared__ int s[1024];
    int t = threadIdx.x;
    int blk = blockIdx.x;
    int i = blk * 1024 + t;
    int v = (i < n) ? a[i] : 0;
    s[t] = v;
    __syncthreads();
    for (int d = 1; d < 1024; d <<= 1) {
        int y = (t >= d) ? s[t - d] : 0;
        __syncthreads();
        s[t] += y;
        __syncthreads();
    }
    int myincl = s[t];
    int total = s[1023];
    if (t == 0)
        __hip_atomic_store(&partials[blk], total | SFLAG,
                           __ATOMIC_RELEASE, __HIP_MEMORY_SCOPE_AGENT);
    int contrib = 0;
    if (t < blk) {
        int pv;
        do {
            pv = __hip_atomic_load(&partials[t], __ATOMIC_ACQUIRE,
                                   __HIP_MEMORY_SCOPE_AGENT);
        } while (!(pv & SFLAG));
        contrib = pv & ~SFLAG;
    }
    __syncthreads();
    s[t] = contrib;
    __syncthreads();
    for (int d = 512; d > 0; d >>= 1) {
        if (t < d) s[t] += s[t + d];
        __syncthreads();
    }
    int excl = s[0];
    if (i < n) a[i] = myincl - v + excl;    // absolute exclusive scan
}

// ---------- CSR pass 3: scatter packed (src<<9 | localTgt), int4 edge loads
__global__ __launch_bounds__(256) void k_phase3(const int* __restrict__ ei, int E,
                                                const int* __restrict__ offs, int NBLK, int NBUCK,
                                                int* __restrict__ tmp) {
    __shared__ int cur[MAXBUCK];
    int tid = threadIdx.x;
    if (tid < NBUCK) cur[tid] = offs[tid * NBLK + blockIdx.x];
    __syncthreads();
    int e0 = blockIdx.x * CHUNK;
    int e1 = min(e0 + CHUNK, E);
    int lim = e1 - e0;
    int lim4 = lim >> 2;
    const int4* __restrict__ rv4 = (const int4*)(ei + e0);
    const int4* __restrict__ cv4 = (const int4*)(ei + E + e0);
    for (int q = tid; q < lim4; q += 256) {
        int4 r = rv4[q];
        int4 c = cv4[q];
        int p0 = atomicAdd(&cur[c.x >> BSH], 1); tmp[p0] = (r.x << BSH) | (c.x & BMASK);
        int p1 = atomicAdd(&cur[c.y >> BSH], 1); tmp[p1] = (r.y << BSH) | (c.y & BMASK);
        int p2 = atomicAdd(&cur[c.z >> BSH], 1); tmp[p2] = (r.z << BSH) | (c.z & BMASK);
        int p3 = atomicAdd(&cur[c.w >> BSH], 1); tmp[p3] = (r.w << BSH) | (c.w & BMASK);
    }
    if (tid < (lim & 3)) {
        int e = e0 + lim4 * 4 + tid;
        int r = ei[e], c = ei[E + e];
        int p = atomicAdd(&cur[c >> BSH], 1);
        tmp[p] = (r << BSH) | (c & BMASK);
    }
}

// ---------- K4: fused [fine counting sort | MFMA gemm], block-range split.
// blocks [0, NBUCK): per-bucket fine sort (512 nodes/bucket, LDS-staged run)
// blocks [NBUCK, NBUCK + N/160): gemm, two independent 16-row pipelines (sub=tid>>8)
__global__ __launch_bounds__(FTH, 1) void k_fine_gemm(const int* __restrict__ tmp,
                                                      const int* __restrict__ offs,
                                                      int NBLK, int NBUCK,
                                                      int N, int E,
                                                      int* __restrict__ sortedRow,
                                                      const int* __restrict__ cnt,
                                                      int* __restrict__ rowStart,
                                                      const float* __restrict__ x,
                                                      const _Float16* __restrict__ Bfrag,
                                                      _Float16* __restrict__ g) {
    __shared__ __align__(16) char smem[SMEM_BYTES];
    int tid = threadIdx.x;
    int blk = blockIdx.x;

    if (blk < NBUCK) {
        // ================= fine counting sort =================
        int* scnt = (int*)smem;
        int* cur  = scnt + 512;
        int* ec   = cur + 512;
        int b = blk;
        int t = tid;
        int start = offs[b * NBLK];
        int end = (b + 1 < NBUCK) ? offs[(b + 1) * NBLK] : E;
        int len = end - start;

        scnt[t] = 0;
        __syncthreads();
        if (len <= ECAP) {
            for (int p = t; p < len; p += FTH) {
                int v = tmp[start + p];
                ec[p] = v;
                atomicAdd(&scnt[v & BMASK], 1);
            }
            __syncthreads();
            int v = scnt[t];
            for (int d = 1; d < 512; d <<= 1) {
                int y = (t >= d) ? scnt[t - d] : 0;
                __syncthreads();
                scnt[t] += y;
                __syncthreads();
            }
            int excl = scnt[t] - v;
            int node = (b << BSH) + t;
            if (node < N) rowStart[node] = start + excl;
            cur[t] = start + excl;
            __syncthreads();
            for (int p = t; p < len; p += FTH) {
                int pr = ec[p];
                int slot = atomicAdd(&cur[pr & BMASK], 1);
                sortedRow[slot] = pr >> BSH;
            }
        } else {
            for (int p = start + t; p < end; p += FTH) atomicAdd(&scnt[tmp[p] & BMASK], 1);
            __syncthreads();
            int v = scnt[t];
            for (int d = 1; d < 512; d <<= 1) {
                int y = (t >= d) ? scnt[t - d] : 0;
                __syncthreads();
                scnt[t] += y;
                __syncthreads();
            }
            int excl = scnt[t] - v;
            int node = (b << BSH) + t;
            if (node < N) rowStart[node] = start + excl;
            cur[t] = start + excl;
            __syncthreads();
            for (int p = start + t; p < end; p += FTH) {
                int pr = tmp[p];
                int slot = atomicAdd(&cur[pr & BMASK], 1);
                sortedRow[slot] = pr >> BSH;
            }
        }
        if (b == NBUCK - 1 && t == 0) rowStart[N] = E;
    } else {
        // ================= gemm: g = fp16( dinv * (x @ Wc^T) ) =================
        int bid = blk - NBUCK;
        int t8   = tid & 255;
        int sub  = tid >> 8;       // 0/1: two independent pipelines
        int lane = t8 & 63;
        int w    = t8 >> 6;        // wave-in-pipeline 0..3
        int quad = lane >> 4;
        int lcol = lane & 15;

        _Float16* xs = ((_Float16*)smem) + sub * (2 * 16 * AROW);

        const half8* Bv = (const half8*)Bfrag;
        half8 b0[8], b1[8];
#pragma unroll
        for (int kk = 0; kk < 8; ++kk) {
            b0[kk] = Bv[(w * 8 + kk) * 64 + lane];
            b1[kk] = Bv[((w + 4) * 8 + kk) * 64 + lane];
        }

        long base = (long)bid * (16 * MT * 2) + (long)sub * (16 * MT);
        for (int t = 0; t < MT; ++t) {
            long m0 = base + t * 16;
            _Float16* xb = xs + (t & 1) * (16 * AROW);
            // WAR-safe: barrier at tile t-1 guaranteed reads of this buffer done.
            const float4* xv = (const float4*)(x + m0 * KDIM);
#pragma unroll
            for (int ii = 0; ii < 4; ++ii) {
                int idx = t8 + ii * 256;        // 16 rows x 64 float4
                int m = idx >> 6, k4 = idx & 63;
                float4 v = xv[idx];
                half4v hv = { (_Float16)v.x, (_Float16)v.y, (_Float16)v.z, (_Float16)v.w };
                *(half4v*)&xb[m * AROW + k4 * 4] = hv;
            }
            __syncthreads();    // block-wide; both pipelines at same phase count

            float4v acc0 = {0.f, 0.f, 0.f, 0.f}, acc1 = {0.f, 0.f, 0.f, 0.f};
#pragma unroll
            for (int kk = 0; kk < 8; ++kk) {
                half8 a = *(const half8*)(&xb[lcol * AROW + kk * 32 + quad * 8]);
                acc0 = __builtin_amdgcn_mfma_f32_16x16x32_f16(a, b0[kk], acc0, 0, 0, 0);
                acc1 = __builtin_amdgcn_mfma_f32_16x16x32_f16(a, b1[kk], acc1, 0, 0, 0);
            }

            // C/D layout: col = lane&15, row = quad*4 + reg
#pragma unroll
            for (int r = 0; r < 4; ++r) {
                long node = m0 + quad * 4 + r;
                float di = rsqrtf((float)(cnt[node] + 1));   // deg = cnt + self-loop
                g[node * NDIM + w * 16 + lcol]        = (_Float16)(acc0[r] * di);
                g[node * NDIM + (w + 4) * 16 + lcol]  = (_Float16)(acc1[r] * di);
            }
        }
    }
}

// ---------- gather + scale + bias + row L2-normalize (unchanged)
__global__ __launch_bounds__(256) void k_gather(const _Float16* __restrict__ g,
                                                const int* __restrict__ rowStart,
                                                const int* __restrict__ sortedRow,
                                                const int* __restrict__ cnt,
                                                const float* __restrict__ bg,
                                                float* __restrict__ out) {
    int lane = threadIdx.x & 63;
    int i = blockIdx.x * 4 + (threadIdx.x >> 6);   // node, N divisible by 4
    const int s = rowStart[i];
    const int e = rowStart[i + 1];
    const int g4  = lane >> 4;   // edge slot within wave: 0..3
    const int r16 = lane & 15;   // dim slot: halfs [r16*8, r16*8+8)

    const half8* __restrict__ gv = (const half8*)g;  // 16 half8 per row

    float acc[8];
#pragma unroll
    for (int j = 0; j < 8; ++j) acc[j] = 0.f;

#if HAS_FDOT2
    const half2v one2 = { (_Float16)1.0f, (_Float16)1.0f };
#endif

    int p = s;
    for (; p + 16 <= e; p += 16) {
        int r0 = sortedRow[p + g4];
        int r1 = sortedRow[p + 4 + g4];
        int r2 = sortedRow[p + 8 + g4];
        int r3 = sortedRow[p + 12 + g4];
        half8 v0 = gv[(size_t)r0 * 16 + r16];
        half8 v1 = gv[(size_t)r1 * 16 + r16];
        half8 v2 = gv[(size_t)r2 * 16 + r16];
        half8 v3 = gv[(size_t)r3 * 16 + r16];
#if HAS_FDOT2
#pragma unroll
        for (int j = 0; j < 8; ++j) {
            half2v a = { v0[j], v1[j] };
            half2v b = { v2[j], v3[j] };
            acc[j] = __builtin_amdgcn_fdot2(a, one2,
                     __builtin_amdgcn_fdot2(b, one2, acc[j], false), false);
        }
#else
#pragma unroll
        for (int j = 0; j < 8; ++j)
            acc[j] += ((float)v0[j] + (float)v1[j]) + ((float)v2[j] + (float)v3[j]);
#endif
    }
    if (p + 8 <= e) {
        int r0 = sortedRow[p + g4];
        int r1 = sortedRow[p + 4 + g4];
        half8 v0 = gv[(size_t)r0 * 16 + r16];
        half8 v1 = gv[(size_t)r1 * 16 + r16];
#if HAS_FDOT2
#pragma unroll
        for (int j = 0; j < 8; ++j) {
            half2v a = { v0[j], v1[j] };
            acc[j] = __builtin_amdgcn_fdot2(a, one2, acc[j], false);
        }
#else
#pragma unroll
        for (int j = 0; j < 8; ++j) acc[j] += (float)v0[j] + (float)v1[j];
#endif
        p += 8;
    }
    if (p + 4 <= e) {
        int r0 = sortedRow[p + g4];
        half8 v0 = gv[(size_t)r0 * 16 + r16];
#pragma unroll
        for (int j = 0; j < 8; ++j) acc[j] += (float)v0[j];
        p += 4;
    }
    if (p + g4 < e) {
        int r0 = sortedRow[p + g4];
        half8 v0 = gv[(size_t)r0 * 16 + r16];
#pragma unroll
        for (int j = 0; j < 8; ++j) acc[j] += (float)v0[j];
    }

#pragma unroll
    for (int j = 0; j < 8; ++j) {
        acc[j] += __shfl_xor(acc[j], 16);
        acc[j] += __shfl_xor(acc[j], 32);
    }

    half8 sv = gv[(size_t)i * 16 + r16];
#pragma unroll
    for (int j = 0; j < 8; ++j) acc[j] += (float)sv[j];

    float di = rsqrtf((float)(cnt[i] + 1));
    float4 b0 = ((const float4*)bg)[r16 * 2];
    float4 b1 = ((const float4*)bg)[r16 * 2 + 1];
    float v[8];
    v[0] = fmaf(di, acc[0], b0.x);
    v[1] = fmaf(di, acc[1], b0.y);
    v[2] = fmaf(di, acc[2], b0.z);
    v[3] = fmaf(di, acc[3], b0.w);
    v[4] = fmaf(di, acc[4], b1.x);
    v[5] = fmaf(di, acc[5], b1.y);
    v[6] = fmaf(di, acc[6], b1.z);
    v[7] = fmaf(di, acc[7], b1.w);

    float sq = 0.f;
#pragma unroll
    for (int j = 0; j < 8; ++j) sq += v[j] * v[j];
    sq += __shfl_xor(sq, 1);
    sq += __shfl_xor(sq, 2);
    sq += __shfl_xor(sq, 4);
    sq += __shfl_xor(sq, 8);
    float scale = 1.0f / fmaxf(sqrtf(sq), 1e-12f);

    if (g4 == 0) {
        float4 o0 = make_float4(v[0] * scale, v[1] * scale, v[2] * scale, v[3] * scale);
        float4 o1 = make_float4(v[4] * scale, v[5] * scale, v[6] * scale, v[7] * scale);
        ((float4*)out)[(size_t)i * 32 + r16 * 2]     = o0;
        ((float4*)out)[(size_t)i * 32 + r16 * 2 + 1] = o1;
    }
}

extern "C" void kernel_launch(void* const* d_in, const int* in_sizes, int n_in,
                              void* d_out, int out_size, void* d_ws, size_t ws_size,
                              hipStream_t stream) {
    const float* x  = (const float*)d_in[0];
    const int*   ei = (const int*)  d_in[1];
    const float* Wp = (const float*)d_in[2];
    const float* Wg = (const float*)d_in[3];
    const float* bg = (const float*)d_in[4];
    float* out = (float*)d_out;

    const int N = in_sizes[0] / KDIM;   // 100000
    const int E = in_sizes[1] / 2;      // 1600000

    const int NBLK  = (E + CHUNK - 1) / CHUNK;   // 500
    const int NBUCK = (N + BMASK) >> BSH;        // 196
    const int NE    = NBLK * NBUCK;              // 98000
    const int NSB   = (NE + 1023) >> 10;         // 96 scan chunks (<=128)
    const int GBLK  = N / (16 * MT * 2);         // 625 gemm blocks (160 rows each)

    // carve workspace (256B aligned)
    char* p = (char*)d_ws;
    auto carve = [&](size_t bytes) { void* r = (void*)p; p += (bytes + 255) & ~(size_t)255; return r; };
    _Float16* g      = (_Float16*)carve((size_t)N * NDIM * 2);  // 25.6 MB
    int*   sortedRow = (int*)  carve((size_t)E * 4);            // 6.4 MB
    int*   tmp       = (int*)  carve((size_t)E * 4);            // 6.4 MB (packed)
    _Float16* Bfrag  = (_Float16*)carve((size_t)KDIM * NDIM * 2);
    int*   cnt       = (int*)  carve((size_t)N * 4);
    int*   rowStart  = (int*)  carve((size_t)(N + 1) * 4);
    int*   hist      = (int*)  carve((size_t)NE * 4);
    int*   partials  = (int*)  carve((size_t)128 * 4);

    hipMemsetAsync(cnt, 0, (size_t)N * 4, stream);
    hipLaunchKernelGGL(k_prep, dim3(NBLK + 128), dim3(256), 0, stream,
                       Wp, Wg, Bfrag, ei, E, hist, NBLK, NBUCK, cnt, partials);
    hipLaunchKernelGGL(k_scan_lb, dim3(NSB), dim3(1024), 0, stream, hist, NE, partials);
    hipLaunchKernelGGL(k_phase3, dim3(NBLK), dim3(256), 0, stream, ei, E, hist, NBLK, NBUCK, tmp);
    hipLaunchKernelGGL(k_fine_gemm, dim3(NBUCK + GBLK), dim3(FTH), 0, stream,
                       tmp, hist, NBLK, NBUCK, N, E, sortedRow, cnt, rowStart, x, Bfrag, g);
    hipLaunchKernelGGL(k_gather, dim3(N / 4), dim3(256), 0, stream,
                       g, rowStart, sortedRow, cnt, bg, out);
}

// Round 8
// 296.603 us; speedup vs baseline: 1.1501x; 1.1501x over previous
//
#include <hip/hip_runtime.h>
#include <hip/hip_fp16.h>

#define NDIM 128     // OUT_DIM
#define KDIM 256     // IN_DIM
#define MT 5         // M-tiles (of 16 rows) per GEMM block
#define AROW 264     // LDS A-row stride in halfs (16B-aligned, breaks pow2)
#define CHUNK 3200   // edges per phase1/phase3 block (500 blocks); divisible by 4
#define BSH 9        // bucket = 512 nodes
#define BMASK 511
#define MAXBUCK 256  // >= NBUCK = ceil(N/512) = 196
#define FTH 512      // k_fine threads
#define ECAP 12032   // k_fine LDS staging capacity (48KB); mean run 8192, max ~8.8K
#define SFLAG 0x40000000

typedef _Float16 half8 __attribute__((ext_vector_type(8)));
typedef _Float16 half4v __attribute__((ext_vector_type(4)));
typedef _Float16 half2v __attribute__((ext_vector_type(2)));
typedef float float4v __attribute__((ext_vector_type(4)));

#if __has_builtin(__builtin_amdgcn_fdot2)
#define HAS_FDOT2 1
#else
#define HAS_FDOT2 0
#endif

// ---------- K1: fused [phase1 histogram | combine_w], block-range split.
// blocks 0..NBLK-1: per-block coarse histogram (bucket = tgt>>9), int4 loads,
//                   4-way wave-replicated LDS counters (cuts atomic contention).
// blocks NBLK..NBLK+127: Wc = Wg @ Wp in MFMA B-fragment layout
// block 0 additionally zeroes the scan-lookback flags (replay-safe).
__global__ __launch_bounds__(256) void k_prep(const float* __restrict__ Wp,
                                              const float* __restrict__ Wg,
                                              _Float16* __restrict__ Bfrag,
                                              const int* __restrict__ ei, int E,
                                              int* __restrict__ hist, int NBLK, int NBUCK,
                                              int* __restrict__ partials) {
    __shared__ int h[4][MAXBUCK];
    int tid = threadIdx.x;
    int blk = blockIdx.x;
    if (blk < NBLK) {
        // ---- phase1
        if (blk == 0 && tid < 128) partials[tid] = 0;   // NSB <= 128
        const int* __restrict__ col = ei + E;
        for (int idx = tid; idx < 4 * MAXBUCK; idx += 256) ((int*)h)[idx] = 0;
        __syncthreads();
        int wv = tid >> 6;                               // wave 0..3
        int* __restrict__ myh = h[wv];
        int e0 = blk * CHUNK;
        int e1 = min(e0 + CHUNK, E);
        int lim4 = (e1 - e0) >> 2;                       // CHUNK divisible by 4
        const int4* __restrict__ cv = (const int4*)(col + e0);
        for (int q = tid; q < lim4; q += 256) {
            int4 c = cv[q];
            atomicAdd(&myh[c.x >> BSH], 1);
            atomicAdd(&myh[c.y >> BSH], 1);
            atomicAdd(&myh[c.z >> BSH], 1);
            atomicAdd(&myh[c.w >> BSH], 1);
        }
        __syncthreads();
        for (int b = tid; b < NBUCK; b += 256)
            hist[b * NBLK + blk] = h[0][b] + h[1][b] + h[2][b] + h[3][b];
    } else {
        // ---- combine_w
        int o = blk - NBLK;      // n: 0..127
        int i = tid;             // k: 0..255
        float acc = 0.f;
#pragma unroll 4
        for (int k = 0; k < 128; ++k) acc = fmaf(Wg[o * 128 + k], Wp[k * 256 + i], acc);
        int kk = i >> 5, r = i & 31, quad = r >> 3, j = r & 7;
        int ntile = o >> 4, lanen = o & 15, lane = quad * 16 + lanen;
        Bfrag[(((ntile * 8 + kk) * 64) + lane) * 8 + j] = (_Float16)acc;
    }
}

// ---------- K2: single-kernel exclusive scan via aggregate lookback.
// 96 blocks x 1024 threads, all co-resident (96 << 256 CUs) -> spin is safe.
__global__ __launch_bounds__(1024) void k_scan_lb(int* __restrict__ a, int n,
                                                  int* __restrict__ partials) {
    __shared__ int s[1024];
    int t = threadIdx.x;
    int blk = blockIdx.x;
    int i = blk * 1024 + t;
    int v = (i < n) ? a[i] : 0;
    s[t] = v;
    __syncthreads();
    for (int d = 1; d < 1024; d <<= 1) {
        int y = (t >= d) ? s[t - d] : 0;
        __syncthreads();
        s[t] += y;
        __syncthreads();
    }
    int myincl = s[t];
    int total = s[1023];
    if (t == 0)
        __hip_atomic_store(&partials[blk], total | SFLAG,
                           __ATOMIC_RELEASE, __HIP_MEMORY_SCOPE_AGENT);
    int contrib = 0;
    if (t < blk) {
        int pv;
        do {
            pv = __hip_atomic_load(&partials[t], __ATOMIC_ACQUIRE,
                                   __HIP_MEMORY_SCOPE_AGENT);
        } while (!(pv & SFLAG));
        contrib = pv & ~SFLAG;
    }
    __syncthreads();
    s[t] = contrib;
    __syncthreads();
    for (int d = 512; d > 0; d >>= 1) {
        if (t < d) s[t] += s[t + d];
        __syncthreads();
    }
    int excl = s[0];
    if (i < n) a[i] = myincl - v + excl;    // absolute exclusive scan
}

// ---------- CSR pass 3: scatter packed (src<<9 | localTgt), int4 edge loads
__global__ __launch_bounds__(256) void k_phase3(const int* __restrict__ ei, int E,
                                                const int* __restrict__ offs, int NBLK, int NBUCK,
                                                int* __restrict__ tmp) {
    __shared__ int cur[MAXBUCK];
    int tid = threadIdx.x;
    if (tid < NBUCK) cur[tid] = offs[tid * NBLK + blockIdx.x];
    __syncthreads();
    int e0 = blockIdx.x * CHUNK;
    int e1 = min(e0 + CHUNK, E);
    int lim4 = (e1 - e0) >> 2;                       // CHUNK divisible by 4
    const int4* __restrict__ rv4 = (const int4*)(ei + e0);
    const int4* __restrict__ cv4 = (const int4*)(ei + E + e0);
    for (int q = tid; q < lim4; q += 256) {
        int4 r = rv4[q];
        int4 c = cv4[q];
        int p0 = atomicAdd(&cur[c.x >> BSH], 1); tmp[p0] = (r.x << BSH) | (c.x & BMASK);
        int p1 = atomicAdd(&cur[c.y >> BSH], 1); tmp[p1] = (r.y << BSH) | (c.y & BMASK);
        int p2 = atomicAdd(&cur[c.z >> BSH], 1); tmp[p2] = (r.z << BSH) | (c.z & BMASK);
        int p3 = atomicAdd(&cur[c.w >> BSH], 1); tmp[p3] = (r.w << BSH) | (c.w & BMASK);
    }
}

// ---------- CSR pass 4: per-bucket fine counting sort (512 nodes/bucket),
// LDS-staged run (reads tmp once), 2-copy replicated count histogram.
__global__ __launch_bounds__(FTH, 1) void k_fine(const int* __restrict__ tmp,
                                                 const int* __restrict__ offs, int NBLK, int NBUCK,
                                                 int N, int E,
                                                 int* __restrict__ sortedRow,
                                                 int* __restrict__ cnt,
                                                 int* __restrict__ rowStart) {
    __shared__ int scnt[512];
    __shared__ int scnt1[512];
    __shared__ int cur[512];
    __shared__ int ec[ECAP];
    int b = blockIdx.x;
    int t = threadIdx.x;
    int start = offs[b * NBLK];
    int end = (b + 1 < NBUCK) ? offs[(b + 1) * NBLK] : E;
    int len = end - start;
    int* __restrict__ myh = ((t >> 6) & 1) ? scnt1 : scnt;   // wave-parity copy

    scnt[t] = 0;
    scnt1[t] = 0;
    __syncthreads();
    if (len <= ECAP) {
        // stage + histogram in one pass
        for (int p = t; p < len; p += FTH) {
            int v = tmp[start + p];
            ec[p] = v;
            atomicAdd(&myh[v & BMASK], 1);
        }
        __syncthreads();
        int v = scnt[t] + scnt1[t];
        scnt[t] = v;
        __syncthreads();
        for (int d = 1; d < 512; d <<= 1) {
            int y = (t >= d) ? scnt[t - d] : 0;
            __syncthreads();
            scnt[t] += y;
            __syncthreads();
        }
        int excl = scnt[t] - v;
        int node = (b << BSH) + t;
        if (node < N) {
            cnt[node] = v;
            rowStart[node] = start + excl;
        }
        cur[t] = start + excl;
        __syncthreads();
        for (int p = t; p < len; p += FTH) {
            int pr = ec[p];
            int slot = atomicAdd(&cur[pr & BMASK], 1);
            sortedRow[slot] = pr >> BSH;
        }
    } else {
        // fallback: two global passes
        for (int p = start + t; p < end; p += FTH) atomicAdd(&myh[tmp[p] & BMASK], 1);
        __syncthreads();
        int v = scnt[t] + scnt1[t];
        scnt[t] = v;
        __syncthreads();
        for (int d = 1; d < 512; d <<= 1) {
            int y = (t >= d) ? scnt[t - d] : 0;
            __syncthreads();
            scnt[t] += y;
            __syncthreads();
        }
        int excl = scnt[t] - v;
        int node = (b << BSH) + t;
        if (node < N) {
            cnt[node] = v;
            rowStart[node] = start + excl;
        }
        cur[t] = start + excl;
        __syncthreads();
        for (int p = start + t; p < end; p += FTH) {
            int pr = tmp[p];
            int slot = atomicAdd(&cur[pr & BMASK], 1);
            sortedRow[slot] = pr >> BSH;
        }
    }
    if (b == NBUCK - 1 && t == 0) rowStart[N] = E;
}

// ---------- g = fp16( dinv * (x @ Wc^T) ) via MFMA 16x16x32 f16, 1 barrier/tile
__global__ __launch_bounds__(256) void k_gemm_mfma(const float* __restrict__ x,
                                                   const _Float16* __restrict__ Bfrag,
                                                   const int* __restrict__ cnt,
                                                   _Float16* __restrict__ g, int nrows) {
    __shared__ __align__(16) _Float16 xs[2][16 * AROW];
    int tid  = threadIdx.x;
    int lane = tid & 63;
    int w    = tid >> 6;      // wave 0..3
    int quad = lane >> 4;
    int lcol = lane & 15;

    const half8* Bv = (const half8*)Bfrag;
    half8 b0[8], b1[8];
#pragma unroll
    for (int kk = 0; kk < 8; ++kk) {
        b0[kk] = Bv[(w * 8 + kk) * 64 + lane];
        b1[kk] = Bv[((w + 4) * 8 + kk) * 64 + lane];
    }

    long base = (long)blockIdx.x * (16 * MT);
    for (int t = 0; t < MT; ++t) {
        long m0 = base + t * 16;
        _Float16* xb = xs[t & 1];
        // WAR-safe: barrier at tile t-1 guaranteed reads of this buffer done.
        const float4* xv = (const float4*)(x + m0 * KDIM);
#pragma unroll
        for (int ii = 0; ii < 4; ++ii) {
            int idx = tid + ii * 256;        // 16 rows x 64 float4
            int m = idx >> 6, k4 = idx & 63;
            float4 v = xv[idx];
            half4v hv = { (_Float16)v.x, (_Float16)v.y, (_Float16)v.z, (_Float16)v.w };
            *(half4v*)&xb[m * AROW + k4 * 4] = hv;
        }
        __syncthreads();

        float4v acc0 = {0.f, 0.f, 0.f, 0.f}, acc1 = {0.f, 0.f, 0.f, 0.f};
#pragma unroll
        for (int kk = 0; kk < 8; ++kk) {
            half8 a = *(const half8*)(&xb[lcol * AROW + kk * 32 + quad * 8]);
            acc0 = __builtin_amdgcn_mfma_f32_16x16x32_f16(a, b0[kk], acc0, 0, 0, 0);
            acc1 = __builtin_amdgcn_mfma_f32_16x16x32_f16(a, b1[kk], acc1, 0, 0, 0);
        }

        // C/D layout: col = lane&15, row = quad*4 + reg
#pragma unroll
        for (int r = 0; r < 4; ++r) {
            long node = m0 + quad * 4 + r;
            float di = rsqrtf((float)(cnt[node] + 1));   // deg = cnt + self-loop
            g[node * NDIM + w * 16 + lcol]        = (_Float16)(acc0[r] * di);
            g[node * NDIM + (w + 4) * 16 + lcol]  = (_Float16)(acc1[r] * di);
        }
    }
}

// ---------- gather + scale + bias + row L2-normalize (unchanged)
__global__ __launch_bounds__(256) void k_gather(const _Float16* __restrict__ g,
                                                const int* __restrict__ rowStart,
                                                const int* __restrict__ sortedRow,
                                                const int* __restrict__ cnt,
                                                const float* __restrict__ bg,
                                                float* __restrict__ out) {
    int lane = threadIdx.x & 63;
    int i = blockIdx.x * 4 + (threadIdx.x >> 6);   // node, N divisible by 4
    const int s = rowStart[i];
    const int e = rowStart[i + 1];
    const int g4  = lane >> 4;   // edge slot within wave: 0..3
    const int r16 = lane & 15;   // dim slot: halfs [r16*8, r16*8+8)

    const half8* __restrict__ gv = (const half8*)g;  // 16 half8 per row

    float acc[8];
#pragma unroll
    for (int j = 0; j < 8; ++j) acc[j] = 0.f;

#if HAS_FDOT2
    const half2v one2 = { (_Float16)1.0f, (_Float16)1.0f };
#endif

    int p = s;
    for (; p + 16 <= e; p += 16) {
        int r0 = sortedRow[p + g4];
        int r1 = sortedRow[p + 4 + g4];
        int r2 = sortedRow[p + 8 + g4];
        int r3 = sortedRow[p + 12 + g4];
        half8 v0 = gv[(size_t)r0 * 16 + r16];
        half8 v1 = gv[(size_t)r1 * 16 + r16];
        half8 v2 = gv[(size_t)r2 * 16 + r16];
        half8 v3 = gv[(size_t)r3 * 16 + r16];
#if HAS_FDOT2
#pragma unroll
        for (int j = 0; j < 8; ++j) {
            half2v a = { v0[j], v1[j] };
            half2v b = { v2[j], v3[j] };
            acc[j] = __builtin_amdgcn_fdot2(a, one2,
                     __builtin_amdgcn_fdot2(b, one2, acc[j], false), false);
        }
#else
#pragma unroll
        for (int j = 0; j < 8; ++j)
            acc[j] += ((float)v0[j] + (float)v1[j]) + ((float)v2[j] + (float)v3[j]);
#endif
    }
    if (p + 8 <= e) {
        int r0 = sortedRow[p + g4];
        int r1 = sortedRow[p + 4 + g4];
        half8 v0 = gv[(size_t)r0 * 16 + r16];
        half8 v1 = gv[(size_t)r1 * 16 + r16];
#if HAS_FDOT2
#pragma unroll
        for (int j = 0; j < 8; ++j) {
            half2v a = { v0[j], v1[j] };
            acc[j] = __builtin_amdgcn_fdot2(a, one2, acc[j], false);
        }
#else
#pragma unroll
        for (int j = 0; j < 8; ++j) acc[j] += (float)v0[j] + (float)v1[j];
#endif
        p += 8;
    }
    if (p + 4 <= e) {
        int r0 = sortedRow[p + g4];
        half8 v0 = gv[(size_t)r0 * 16 + r16];
#pragma unroll
        for (int j = 0; j < 8; ++j) acc[j] += (float)v0[j];
        p += 4;
    }
    if (p + g4 < e) {
        int r0 = sortedRow[p + g4];
        half8 v0 = gv[(size_t)r0 * 16 + r16];
#pragma unroll
        for (int j = 0; j < 8; ++j) acc[j] += (float)v0[j];
    }

#pragma unroll
    for (int j = 0; j < 8; ++j) {
        acc[j] += __shfl_xor(acc[j], 16);
        acc[j] += __shfl_xor(acc[j], 32);
    }

    half8 sv = gv[(size_t)i * 16 + r16];
#pragma unroll
    for (int j = 0; j < 8; ++j) acc[j] += (float)sv[j];

    float di = rsqrtf((float)(cnt[i] + 1));
    float4 b0 = ((const float4*)bg)[r16 * 2];
    float4 b1 = ((const float4*)bg)[r16 * 2 + 1];
    float v[8];
    v[0] = fmaf(di, acc[0], b0.x);
    v[1] = fmaf(di, acc[1], b0.y);
    v[2] = fmaf(di, acc[2], b0.z);
    v[3] = fmaf(di, acc[3], b0.w);
    v[4] = fmaf(di, acc[4], b1.x);
    v[5] = fmaf(di, acc[5], b1.y);
    v[6] = fmaf(di, acc[6], b1.z);
    v[7] = fmaf(di, acc[7], b1.w);

    float sq = 0.f;
#pragma unroll
    for (int j = 0; j < 8; ++j) sq += v[j] * v[j];
    sq += __shfl_xor(sq, 1);
    sq += __shfl_xor(sq, 2);
    sq += __shfl_xor(sq, 4);
    sq += __shfl_xor(sq, 8);
    float scale = 1.0f / fmaxf(sqrtf(sq), 1e-12f);

    if (g4 == 0) {
        float4 o0 = make_float4(v[0] * scale, v[1] * scale, v[2] * scale, v[3] * scale);
        float4 o1 = make_float4(v[4] * scale, v[5] * scale, v[6] * scale, v[7] * scale);
        ((float4*)out)[(size_t)i * 32 + r16 * 2]     = o0;
        ((float4*)out)[(size_t)i * 32 + r16 * 2 + 1] = o1;
    }
}

extern "C" void kernel_launch(void* const* d_in, const int* in_sizes, int n_in,
                              void* d_out, int out_size, void* d_ws, size_t ws_size,
                              hipStream_t stream) {
    const float* x  = (const float*)d_in[0];
    const int*   ei = (const int*)  d_in[1];
    const float* Wp = (const float*)d_in[2];
    const float* Wg = (const float*)d_in[3];
    const float* bg = (const float*)d_in[4];
    float* out = (float*)d_out;

    const int N = in_sizes[0] / KDIM;   // 100000
    const int E = in_sizes[1] / 2;      // 1600000

    const int NBLK  = (E + CHUNK - 1) / CHUNK;   // 500
    const int NBUCK = (N + BMASK) >> BSH;        // 196
    const int NE    = NBLK * NBUCK;              // 98000
    const int NSB   = (NE + 1023) >> 10;         // 96 scan chunks (<=128)

    // carve workspace (256B aligned)
    char* p = (char*)d_ws;
    auto carve = [&](size_t bytes) { void* r = (void*)p; p += (bytes + 255) & ~(size_t)255; return r; };
    _Float16* g      = (_Float16*)carve((size_t)N * NDIM * 2);  // 25.6 MB
    int*   sortedRow = (int*)  carve((size_t)E * 4);            // 6.4 MB
    int*   tmp       = (int*)  carve((size_t)E * 4);            // 6.4 MB (packed)
    _Float16* Bfrag  = (_Float16*)carve((size_t)KDIM * NDIM * 2);
    int*   cnt       = (int*)  carve((size_t)N * 4);
    int*   rowStart  = (int*)  carve((size_t)(N + 1) * 4);
    int*   hist      = (int*)  carve((size_t)NE * 4);
    int*   partials  = (int*)  carve((size_t)128 * 4);

    hipLaunchKernelGGL(k_prep, dim3(NBLK + 128), dim3(256), 0, stream,
                       Wp, Wg, Bfrag, ei, E, hist, NBLK, NBUCK, partials);
    hipLaunchKernelGGL(k_scan_lb, dim3(NSB), dim3(1024), 0, stream, hist, NE, partials);
    hipLaunchKernelGGL(k_phase3, dim3(NBLK), dim3(256), 0, stream, ei, E, hist, NBLK, NBUCK, tmp);
    hipLaunchKernelGGL(k_fine, dim3(NBUCK), dim3(FTH), 0, stream, tmp, hist, NBLK, NBUCK, N, E,
                       sortedRow, cnt, rowStart);
    hipLaunchKernelGGL(k_gemm_mfma, dim3(N / (16 * MT)), dim3(256), 0, stream, x, Bfrag, cnt, g, N);
    hipLaunchKernelGGL(k_gather, dim3(N / 4), dim3(256), 0, stream,
                       g, rowStart, sortedRow, cnt, bg, out);
}